// Round 1
// baseline (323.422 us; speedup 1.0000x reference)
//
#include <hip/hip_runtime.h>

// Depthwise 4x4 binomial blur, fp32.
// x: (8, 64, 512, 512), pad (1,1,1,1), stride 1 -> out: (8, 64, 511, 511)
// kernel = ([1,3,3,1] outer [1,3,3,1]) / 64  (separable)

constexpr int H  = 512;
constexpr int W  = 512;
constexpr int OH = 511;
constexpr int OW = 511;
constexpr int BC = 8 * 64;   // batch*channels planes

constexpr int TW = 64;       // output tile width
constexpr int TH = 16;       // output tile height
constexpr int SW = TW + 3;   // 67 input cols needed
constexpr int SH = TH + 3;   // 19 input rows needed
constexpr int SSTRIDE = SW + 1; // 68 -> avoid power-of-2 stride conflicts

__global__ __launch_bounds__(256, 4)
void blur_kernel(const float* __restrict__ in, float* __restrict__ out)
{
    __shared__ float s[SH][SSTRIDE];

    const int tx0 = blockIdx.x * TW;
    const int ty0 = blockIdx.y * TH;
    const int bc  = blockIdx.z;

    const float* __restrict__ inp  = in  + (size_t)bc * (H * W);
    float* __restrict__       outp = out + (size_t)bc * (OH * OW);

    const int tid = threadIdx.x;

    // ---- stage input tile (with zero-padded halo) into LDS ----
    #pragma unroll
    for (int idx = tid; idx < SH * SW; idx += 256) {
        const int r  = idx / SW;
        const int c  = idx - r * SW;
        const int gy = ty0 - 1 + r;   // input row (pad offset -1)
        const int gx = tx0 - 1 + c;   // input col
        float v = 0.0f;
        if ((unsigned)gy < (unsigned)H && (unsigned)gx < (unsigned)W)
            v = inp[(size_t)gy * W + gx];
        s[r][c] = v;
    }
    __syncthreads();

    // ---- compute: each wave owns a 4-row strip; separable filter ----
    const int x      = tid & 63;     // output col within tile (lane)
    const int ystrip = tid >> 6;     // 0..3 (one wave each)
    const int r0     = ystrip * 4;   // base LDS row of this strip

    // horizontal pass: h[r] for LDS rows r0 .. r0+6
    float h[7];
    #pragma unroll
    for (int r = 0; r < 7; ++r) {
        const float a = s[r0 + r][x + 0];
        const float b = s[r0 + r][x + 1];
        const float c = s[r0 + r][x + 2];
        const float d = s[r0 + r][x + 3];
        h[r] = a + 3.0f * b + 3.0f * c + d;
    }

    const int ox = tx0 + x;
    if (ox < OW) {
        #pragma unroll
        for (int k = 0; k < 4; ++k) {
            const int oy = ty0 + r0 + k;
            if (oy < OH) {
                const float v = (h[k] + 3.0f * h[k + 1] + 3.0f * h[k + 2] + h[k + 3])
                                * (1.0f / 64.0f);
                outp[(size_t)oy * OW + ox] = v;
            }
        }
    }
}

extern "C" void kernel_launch(void* const* d_in, const int* in_sizes, int n_in,
                              void* d_out, int out_size, void* d_ws, size_t ws_size,
                              hipStream_t stream)
{
    const float* x = (const float*)d_in[0];
    float* out = (float*)d_out;

    dim3 grid((OW + TW - 1) / TW,   // 8
              (OH + TH - 1) / TH,   // 32
              BC);                  // 512
    dim3 block(256);
    blur_kernel<<<grid, block, 0, stream>>>(x, out);
}